// Round 1
// baseline (668.798 us; speedup 1.0000x reference)
//
#include <hip/hip_runtime.h>
#include <math.h>

#define BS 128
#define NN 320
#define H1 8
#define F1 18
#define D1 144
#define H2C 4
#define F2 46
#define D2 184
#define FC0 104
#define FC1 45
#define FC2 84
#define LRA 0.2f

__device__ __forceinline__ float wave_max64(float v) {
    #pragma unroll
    for (int off = 32; off > 0; off >>= 1)
        v = fmaxf(v, __shfl_xor(v, off, 64));
    return v;
}
__device__ __forceinline__ float wave_sum64(float v) {
    #pragma unroll
    for (int off = 32; off > 0; off >>= 1)
        v += __shfl_xor(v, off, 64);
    return v;
}

// ---------------- K0: CSR build + layer-1 attention constants ----------------
__global__ void k_csr(const float* __restrict__ adj, int* __restrict__ cols,
                      int* __restrict__ len, const float* __restrict__ W1,
                      const float* __restrict__ a1, float* __restrict__ c1s,
                      float* __restrict__ c1d) {
    int row = blockIdx.x;
    int lane = threadIdx.x;  // 64 threads
    if (row < NN) {
        int base = 0;
        for (int c0 = 0; c0 < NN; c0 += 64) {
            int j = c0 + lane;
            bool p = (j < NN) && (adj[row * NN + j] > 0.f);
            unsigned long long m = __ballot(p);
            if (p) {
                int pos = base + __popcll(m & ((1ull << lane) - 1ull));
                cols[row * NN + pos] = j;
            }
            base += __popcll(m);
        }
        if (lane == 0) len[row] = base;
    } else {
        int h = lane;
        if (h < H1) {
            float s = 0.f, d = 0.f;
            for (int f = 0; f < F1; ++f) {
                float w = W1[h * F1 + f];
                s += w * a1[h * 2 * F1 + f];
                d += w * a1[h * 2 * F1 + F1 + f];
            }
            c1s[h] = s;
            c1d[h] = d;
        }
    }
}

// ---------------- K1: layer-1 GAT (rank-1 structure) ----------------
__global__ __launch_bounds__(256) void k_gat1(
    const float* __restrict__ xn, const int* __restrict__ cols,
    const int* __restrict__ len, const float* __restrict__ W1,
    const float* __restrict__ c1s, const float* __restrict__ c1d,
    float* __restrict__ out1) {
    int b = blockIdx.x >> 3;
    int h = blockIdx.x & 7;
    __shared__ float xb[NN];
    __shared__ float w1h[F1];
    int tid = threadIdx.x;
    for (int t = tid; t < NN; t += 256) xb[t] = xn[b * NN + t];
    if (tid < F1) w1h[tid] = W1[h * F1 + tid];
    __syncthreads();
    float cs = c1s[h], cd = c1d[h];
    int wave = tid >> 6, lane = tid & 63;
    for (int i = wave; i < NN; i += 4) {
        float u = xb[i] * cs;
        int L = len[i];
        float m = -1e30f;
        for (int c0 = 0; c0 < L; c0 += 64) {
            int idx = c0 + lane;
            float e = -1e30f;
            if (idx < L) {
                float t = u + xb[cols[i * NN + idx]] * cd;
                e = t > 0.f ? t : LRA * t;
            }
            m = fmaxf(m, wave_max64(e));
        }
        float den = 0.f, num = 0.f;
        for (int c0 = 0; c0 < L; c0 += 64) {
            int idx = c0 + lane;
            float w = 0.f, wx = 0.f;
            if (idx < L) {
                float xc = xb[cols[i * NN + idx]];
                float t = u + xc * cd;
                t = t > 0.f ? t : LRA * t;
                w = expf(t - m);
                wx = w * xc;
            }
            den += wave_sum64(w);
            num += wave_sum64(wx);
        }
        float s = num / den;
        if (lane < F1) {
            float v = s * w1h[lane];
            v = v > 0.f ? v : expm1f(v);
            out1[(b * NN + i) * D1 + h * F1 + lane] = v;
        }
    }
}

// ---------------- K2: pool1 + x0 copy into d_out ----------------
__global__ void k_pool1(const float* __restrict__ out1,
                        const float* __restrict__ xn,
                        const float* __restrict__ p1w,
                        const float* __restrict__ p1b,
                        float* __restrict__ dout) {
    int bn = blockIdx.x * 256 + threadIdx.x;
    if (bn >= BS * NN) return;
    int b = bn / NN, n = bn % NN;
    const float4* r = (const float4*)(out1 + bn * D1);
    const float4* p = (const float4*)p1w;
    float acc = 0.f;
    #pragma unroll
    for (int q = 0; q < D1 / 4; ++q) {
        float4 a = r[q], w = p[q];
        acc += a.x * w.x + a.y * w.y + a.z * w.z + a.w * w.w;
    }
    dout[b * 960 + 320 + n] = acc + p1b[0];
    dout[b * 960 + n] = xn[bn];
}

// ---------------- K3: h2 = out1 @ W2 (+ es2/ed2 epilogue) ----------------
// 64 rows x 184 cols per block; 128 threads = 32 row-pairs x 4 heads.
#define KC 24
__global__ __launch_bounds__(128) void k_gemm2(
    const float* __restrict__ out1, const float* __restrict__ W2,
    const float* __restrict__ a2, float* __restrict__ h2,
    float* __restrict__ es2, float* __restrict__ ed2) {
    __shared__ float xt[64 * 145];
    __shared__ float wt[KC * 192];
    int tid = threadIdx.x;
    int r0 = blockIdx.x * 64;
    for (int q = tid; q < 64 * 36; q += 128) {
        int row = q / 36, k4 = q % 36;
        float4 v = *(const float4*)(out1 + (r0 + row) * D1 + 4 * k4);
        float* dst = &xt[row * 145 + 4 * k4];
        dst[0] = v.x; dst[1] = v.y; dst[2] = v.z; dst[3] = v.w;
    }
    int rg = tid >> 2;   // 0..31 -> rows 2rg, 2rg+1
    int h = tid & 3;
    float acc0[48], acc1[48];
    #pragma unroll
    for (int f = 0; f < 48; ++f) { acc0[f] = 0.f; acc1[f] = 0.f; }
    for (int kc = 0; kc < 144 / KC; ++kc) {
        if (kc) __syncthreads();
        for (int q = tid; q < KC * 184; q += 128) {
            int kl = q / 184, c = q % 184;
            int hh = c / 46, f = c % 46;
            wt[kl * 192 + hh * 48 + f] = W2[(hh * 144 + kc * KC + kl) * 46 + f];
        }
        for (int q = tid; q < KC * 8; q += 128) {
            int kl = q >> 3, z = q & 7;
            wt[kl * 192 + (z >> 1) * 48 + 46 + (z & 1)] = 0.f;
        }
        __syncthreads();
        for (int kl = 0; kl < KC; ++kl) {
            int k = kc * KC + kl;
            float xv0 = xt[(2 * rg) * 145 + k];
            float xv1 = xt[(2 * rg + 1) * 145 + k];
            const float4* wrow = (const float4*)&wt[kl * 192 + h * 48];
            #pragma unroll
            for (int q = 0; q < 12; ++q) {
                float4 w = wrow[q];
                acc0[4*q+0] += xv0 * w.x; acc0[4*q+1] += xv0 * w.y;
                acc0[4*q+2] += xv0 * w.z; acc0[4*q+3] += xv0 * w.w;
                acc1[4*q+0] += xv1 * w.x; acc1[4*q+1] += xv1 * w.y;
                acc1[4*q+2] += xv1 * w.z; acc1[4*q+3] += xv1 * w.w;
            }
        }
    }
    int b = r0 / NN;
    int nbase = r0 % NN;
    {
        int n = nbase + 2 * rg;
        float es = 0.f, ed = 0.f;
        #pragma unroll
        for (int f = 0; f < 46; ++f) {
            es += acc0[f] * a2[h * 92 + f];
            ed += acc0[f] * a2[h * 92 + 46 + f];
        }
        float* dst = h2 + ((b * H2C + h) * NN + n) * F2;
        #pragma unroll
        for (int f = 0; f < 46; ++f) dst[f] = acc0[f];
        es2[(b * H2C + h) * NN + n] = es;
        ed2[(b * H2C + h) * NN + n] = ed;
    }
    {
        int n = nbase + 2 * rg + 1;
        float es = 0.f, ed = 0.f;
        #pragma unroll
        for (int f = 0; f < 46; ++f) {
            es += acc1[f] * a2[h * 92 + f];
            ed += acc1[f] * a2[h * 92 + 46 + f];
        }
        float* dst = h2 + ((b * H2C + h) * NN + n) * F2;
        #pragma unroll
        for (int f = 0; f < 46; ++f) dst[f] = acc1[f];
        es2[(b * H2C + h) * NN + n] = es;
        ed2[(b * H2C + h) * NN + n] = ed;
    }
}

// ---------------- K4: layer-2 GAT attention + fused pool2 partials ----------
__global__ __launch_bounds__(256) void k_gat2(
    const float* __restrict__ h2, const float* __restrict__ es2,
    const float* __restrict__ ed2, const int* __restrict__ cols,
    const int* __restrict__ len, const float* __restrict__ p2w,
    float* __restrict__ part2) {
    int b = blockIdx.x >> 2, h = blockIdx.x & 3;
    __shared__ float ht[NN * F2];   // 58880 B
    __shared__ float edl[NN];
    __shared__ float esl[NN];
    int tid = threadIdx.x;
    const float* hp = h2 + (b * H2C + h) * NN * F2;
    for (int q = tid; q < NN * F2 / 4; q += 256)
        ((float4*)ht)[q] = ((const float4*)hp)[q];
    const float* edp = ed2 + (b * H2C + h) * NN;
    const float* esp = es2 + (b * H2C + h) * NN;
    for (int t = tid; t < NN; t += 256) { edl[t] = edp[t]; esl[t] = esp[t]; }
    __syncthreads();
    int wave = tid >> 6, lane = tid & 63;
    int laneF = lane < F2 ? lane : 0;
    float pw = (lane < F2) ? p2w[h * F2 + lane] : 0.f;
    for (int i = wave; i < NN; i += 4) {
        float u = esl[i];
        int L = len[i];
        float m = -1e30f;
        for (int c0 = 0; c0 < L; c0 += 64) {
            int idx = c0 + lane;
            float e = -1e30f;
            if (idx < L) {
                float t = u + edl[cols[i * NN + idx]];
                e = t > 0.f ? t : LRA * t;
            }
            m = fmaxf(m, wave_max64(e));
        }
        float acc = 0.f, den = 0.f;
        for (int c0 = 0; c0 < L; c0 += 64) {
            int idx = c0 + lane;
            int cl = (L - c0) < 64 ? (L - c0) : 64;
            float w = 0.f;
            int col = 0;
            if (idx < L) {
                col = cols[i * NN + idx];
                float t = u + edl[col];
                t = t > 0.f ? t : LRA * t;
                w = expf(t - m);
            }
            den += wave_sum64(w);
            for (int j = 0; j < cl; ++j) {
                float wj = __shfl(w, j, 64);
                int cj = __shfl(col, j, 64);
                acc += wj * ht[cj * F2 + laneF];
            }
        }
        float v = acc / den;
        v = v > 0.f ? v : expm1f(v);
        float pv = (lane < F2) ? v * pw : 0.f;
        float s = wave_sum64(pv);
        if (lane == 0) part2[(b * H2C + h) * NN + i] = s;
    }
}

// ---------------- K5: x2 combine + FC head ----------------
__global__ __launch_bounds__(128) void k_head(
    float* __restrict__ dout, const float* __restrict__ part2,
    const float* __restrict__ p2b, const float* __restrict__ e1w,
    const float* __restrict__ e1b, const float* __restrict__ e2w,
    const float* __restrict__ e2b, const float* __restrict__ e3w,
    const float* __restrict__ e3b, const float* __restrict__ cw,
    const float* __restrict__ cb) {
    int b = blockIdx.x;
    int tid = threadIdx.x;
    __shared__ float xc[960];
    __shared__ float h1[FC0];
    __shared__ float hh[FC1];
    __shared__ float ft[FC2];
    for (int t = tid; t < 640; t += 128) xc[t] = dout[b * 960 + t];
    for (int t = tid; t < NN; t += 128) {
        float s = p2b[0];
        #pragma unroll
        for (int h = 0; h < H2C; ++h) s += part2[(b * H2C + h) * NN + t];
        xc[640 + t] = s;
        dout[b * 960 + 640 + t] = s;
    }
    __syncthreads();
    if (tid < FC0) {
        float a = e1b[tid];
        for (int k = 0; k < 960; ++k) a += xc[k] * e1w[k * FC0 + tid];
        h1[tid] = a > 0.f ? a : expm1f(a);
    }
    __syncthreads();
    if (tid < FC1) {
        float a = e2b[tid];
        for (int k = 0; k < FC0; ++k) a += h1[k] * e2w[k * FC1 + tid];
        hh[tid] = a > 0.f ? a : expm1f(a);
    }
    __syncthreads();
    if (tid < FC2) {
        float a = e3b[tid];
        for (int k = 0; k < FC1; ++k) a += hh[k] * e3w[k * FC2 + tid];
        a = a > 0.f ? a : expm1f(a);
        ft[tid] = a;
        dout[BS * 960 + b * FC2 + tid] = a;
    }
    __syncthreads();
    if (tid < 64) {
        float v = 0.f;
        for (int t = tid; t < FC2; t += 64) v += ft[t] * cw[t];
        v = wave_sum64(v);
        if (tid == 0) dout[BS * 960 + BS * FC2 + b] = v + cb[0];
    }
}

extern "C" void kernel_launch(void* const* d_in, const int* in_sizes, int n_in,
                              void* d_out, int out_size, void* d_ws,
                              size_t ws_size, hipStream_t stream) {
    const float* xn  = (const float*)d_in[0];
    const float* adj = (const float*)d_in[1];
    const float* W1  = (const float*)d_in[2];
    const float* a1  = (const float*)d_in[3];
    const float* W2  = (const float*)d_in[4];
    const float* a2  = (const float*)d_in[5];
    const float* p1w = (const float*)d_in[6];
    const float* p1b = (const float*)d_in[7];
    const float* p2w = (const float*)d_in[8];
    const float* p2b = (const float*)d_in[9];
    const float* e1w = (const float*)d_in[10];
    const float* e1b = (const float*)d_in[11];
    const float* e2w = (const float*)d_in[12];
    const float* e2b = (const float*)d_in[13];
    const float* e3w = (const float*)d_in[14];
    const float* e3b = (const float*)d_in[15];
    const float* cw  = (const float*)d_in[16];
    const float* cb  = (const float*)d_in[17];

    char* ws = (char*)d_ws;
    int*   csr_len  = (int*)ws;                       // 1280 B
    float* c1s      = (float*)(ws + 1280);            // 32 B
    float* c1d      = (float*)(ws + 1312);            // 32 B (pad to 1536)
    int*   csr_cols = (int*)(ws + 1536);              // 409600 -> 411136
    float* out1     = (float*)(ws + 411136);          // 23592960 -> 24004096
    float* h2       = (float*)(ws + 24004096);        // 30146560 -> 54150656
    float* es2      = (float*)(ws + 54150656);        // 655360 -> 54806016
    float* ed2      = (float*)(ws + 54806016);        // 655360 -> 55461376
    float* part2    = (float*)(ws + 55461376);        // 655360 -> 56116736
    float* dout     = (float*)d_out;

    k_csr<<<NN + 1, 64, 0, stream>>>(adj, csr_cols, csr_len, W1, a1, c1s, c1d);
    k_gat1<<<BS * H1, 256, 0, stream>>>(xn, csr_cols, csr_len, W1, c1s, c1d, out1);
    k_pool1<<<(BS * NN + 255) / 256, 256, 0, stream>>>(out1, xn, p1w, p1b, dout);
    k_gemm2<<<BS * NN / 64, 128, 0, stream>>>(out1, W2, a2, h2, es2, ed2);
    k_gat2<<<BS * H2C, 256, 0, stream>>>(h2, es2, ed2, csr_cols, csr_len, p2w, part2);
    k_head<<<BS, 128, 0, stream>>>(dout, part2, p2b, e1w, e1b, e2w, e2b, e3w, e3b, cw, cb);
}

// Round 2
// 478.023 us; speedup vs baseline: 1.3991x; 1.3991x over previous
//
#include <hip/hip_runtime.h>
#include <hip/hip_bf16.h>
#include <math.h>

#define BS 128
#define NN 320
#define H1 8
#define F1 18
#define D1 144
#define H2C 4
#define F2 46
#define D2 184
#define FC0 104
#define FC1 45
#define FC2 84
#define LRA 0.2f

__device__ __forceinline__ float wave_max64(float v) {
    #pragma unroll
    for (int off = 32; off > 0; off >>= 1)
        v = fmaxf(v, __shfl_xor(v, off, 64));
    return v;
}
__device__ __forceinline__ float wave_sum64(float v) {
    #pragma unroll
    for (int off = 32; off > 0; off >>= 1)
        v += __shfl_xor(v, off, 64);
    return v;
}

// ---------------- K0: CSR build + layer-1 attention constants ----------------
__global__ void k_csr(const float* __restrict__ adj, int* __restrict__ cols,
                      int* __restrict__ len, const float* __restrict__ W1,
                      const float* __restrict__ a1, float* __restrict__ c1s,
                      float* __restrict__ c1d) {
    int row = blockIdx.x;
    int lane = threadIdx.x;  // 64 threads
    if (row < NN) {
        int base = 0;
        for (int c0 = 0; c0 < NN; c0 += 64) {
            int j = c0 + lane;
            bool p = (j < NN) && (adj[row * NN + j] > 0.f);
            unsigned long long m = __ballot(p);
            if (p) {
                int pos = base + __popcll(m & ((1ull << lane) - 1ull));
                cols[row * NN + pos] = j;
            }
            base += __popcll(m);
        }
        if (lane == 0) len[row] = base;
    } else {
        int h = lane;
        if (h < H1) {
            float s = 0.f, d = 0.f;
            for (int f = 0; f < F1; ++f) {
                float w = W1[h * F1 + f];
                s += w * a1[h * 2 * F1 + f];
                d += w * a1[h * 2 * F1 + F1 + f];
            }
            c1s[h] = s;
            c1d[h] = d;
        }
    }
}

// ---------------- K1: layer-1 GAT (rank-1 structure) ----------------
__global__ __launch_bounds__(256) void k_gat1(
    const float* __restrict__ xn, const int* __restrict__ cols,
    const int* __restrict__ len, const float* __restrict__ W1,
    const float* __restrict__ c1s, const float* __restrict__ c1d,
    float* __restrict__ out1) {
    int b = blockIdx.x >> 3;
    int h = blockIdx.x & 7;
    __shared__ float xb[NN];
    __shared__ float w1h[F1];
    int tid = threadIdx.x;
    for (int t = tid; t < NN; t += 256) xb[t] = xn[b * NN + t];
    if (tid < F1) w1h[tid] = W1[h * F1 + tid];
    __syncthreads();
    float cs = c1s[h], cd = c1d[h];
    int wave = tid >> 6, lane = tid & 63;
    for (int i = wave; i < NN; i += 4) {
        float u = xb[i] * cs;
        int L = len[i];
        float s;
        if (L <= 64) {   // fast path: everything in registers, one pass
            bool act = lane < L;
            int col = act ? cols[i * NN + lane] : 0;
            float xc = act ? xb[col] : 0.f;
            float t = u + xc * cd;
            t = t > 0.f ? t : LRA * t;
            float e = act ? t : -1e30f;
            float m = wave_max64(e);
            float w = act ? expf(e - m) : 0.f;
            float den = wave_sum64(w);
            float num = wave_sum64(w * xc);
            s = num / den;
        } else {
            float m = -1e30f;
            for (int c0 = 0; c0 < L; c0 += 64) {
                int idx = c0 + lane;
                float e = -1e30f;
                if (idx < L) {
                    float t = u + xb[cols[i * NN + idx]] * cd;
                    e = t > 0.f ? t : LRA * t;
                }
                m = fmaxf(m, wave_max64(e));
            }
            float den = 0.f, num = 0.f;
            for (int c0 = 0; c0 < L; c0 += 64) {
                int idx = c0 + lane;
                float w = 0.f, wx = 0.f;
                if (idx < L) {
                    float xc = xb[cols[i * NN + idx]];
                    float t = u + xc * cd;
                    t = t > 0.f ? t : LRA * t;
                    w = expf(t - m);
                    wx = w * xc;
                }
                den += wave_sum64(w);
                num += wave_sum64(wx);
            }
            s = num / den;
        }
        if (lane < F1) {
            float v = s * w1h[lane];
            v = v > 0.f ? v : expm1f(v);
            out1[(b * NN + i) * D1 + h * F1 + lane] = v;
        }
    }
}

// ---------------- K2: pool1 + x0 copy into d_out ----------------
__global__ void k_pool1(const float* __restrict__ out1,
                        const float* __restrict__ xn,
                        const float* __restrict__ p1w,
                        const float* __restrict__ p1b,
                        float* __restrict__ dout) {
    int bn = blockIdx.x * 256 + threadIdx.x;
    if (bn >= BS * NN) return;
    int b = bn / NN, n = bn % NN;
    const float4* r = (const float4*)(out1 + bn * D1);
    const float4* p = (const float4*)p1w;
    float acc = 0.f;
    #pragma unroll
    for (int q = 0; q < D1 / 4; ++q) {
        float4 a = r[q], w = p[q];
        acc += a.x * w.x + a.y * w.y + a.z * w.z + a.w * w.w;
    }
    dout[b * 960 + 320 + n] = acc + p1b[0];
    dout[b * 960 + n] = xn[bn];
}

// ---------------- K3: h2 = out1 @ W2 (+ es2/ed2 epilogue) ----------------
// 64 rows x 184 cols per block; 128 threads = 32 row-pairs x 4 heads.
#define KC 24
__global__ __launch_bounds__(128) void k_gemm2(
    const float* __restrict__ out1, const float* __restrict__ W2,
    const float* __restrict__ a2, float* __restrict__ h2,
    float* __restrict__ es2, float* __restrict__ ed2) {
    __shared__ float xt[64 * 145];
    __shared__ float wt[KC * 192];
    int tid = threadIdx.x;
    int r0 = blockIdx.x * 64;
    for (int q = tid; q < 64 * 36; q += 128) {
        int row = q / 36, k4 = q % 36;
        float4 v = *(const float4*)(out1 + (r0 + row) * D1 + 4 * k4);
        float* dst = &xt[row * 145 + 4 * k4];
        dst[0] = v.x; dst[1] = v.y; dst[2] = v.z; dst[3] = v.w;
    }
    int rg = tid >> 2;   // 0..31 -> rows 2rg, 2rg+1
    int h = tid & 3;
    float acc0[48], acc1[48];
    #pragma unroll
    for (int f = 0; f < 48; ++f) { acc0[f] = 0.f; acc1[f] = 0.f; }
    for (int kc = 0; kc < 144 / KC; ++kc) {
        if (kc) __syncthreads();
        for (int q = tid; q < KC * 184; q += 128) {
            int kl = q / 184, c = q % 184;
            int hh = c / 46, f = c % 46;
            wt[kl * 192 + hh * 48 + f] = W2[(hh * 144 + kc * KC + kl) * 46 + f];
        }
        for (int q = tid; q < KC * 8; q += 128) {
            int kl = q >> 3, z = q & 7;
            wt[kl * 192 + (z >> 1) * 48 + 46 + (z & 1)] = 0.f;
        }
        __syncthreads();
        for (int kl = 0; kl < KC; ++kl) {
            int k = kc * KC + kl;
            float xv0 = xt[(2 * rg) * 145 + k];
            float xv1 = xt[(2 * rg + 1) * 145 + k];
            const float4* wrow = (const float4*)&wt[kl * 192 + h * 48];
            #pragma unroll
            for (int q = 0; q < 12; ++q) {
                float4 w = wrow[q];
                acc0[4*q+0] += xv0 * w.x; acc0[4*q+1] += xv0 * w.y;
                acc0[4*q+2] += xv0 * w.z; acc0[4*q+3] += xv0 * w.w;
                acc1[4*q+0] += xv1 * w.x; acc1[4*q+1] += xv1 * w.y;
                acc1[4*q+2] += xv1 * w.z; acc1[4*q+3] += xv1 * w.w;
            }
        }
    }
    int b = r0 / NN;
    int nbase = r0 % NN;
    {
        int n = nbase + 2 * rg;
        float es = 0.f, ed = 0.f;
        #pragma unroll
        for (int f = 0; f < 46; ++f) {
            es += acc0[f] * a2[h * 92 + f];
            ed += acc0[f] * a2[h * 92 + 46 + f];
        }
        float* dst = h2 + ((b * H2C + h) * NN + n) * F2;
        #pragma unroll
        for (int f = 0; f < 46; ++f) dst[f] = acc0[f];
        es2[(b * H2C + h) * NN + n] = es;
        ed2[(b * H2C + h) * NN + n] = ed;
    }
    {
        int n = nbase + 2 * rg + 1;
        float es = 0.f, ed = 0.f;
        #pragma unroll
        for (int f = 0; f < 46; ++f) {
            es += acc1[f] * a2[h * 92 + f];
            ed += acc1[f] * a2[h * 92 + 46 + f];
        }
        float* dst = h2 + ((b * H2C + h) * NN + n) * F2;
        #pragma unroll
        for (int f = 0; f < 46; ++f) dst[f] = acc1[f];
        es2[(b * H2C + h) * NN + n] = es;
        ed2[(b * H2C + h) * NN + n] = ed;
    }
}

// ---------------- K4: layer-2 GAT attention + fused pool2 partials ----------
// Restructured: per wave, phase A computes softmax weights (lanes=neighbors)
// into an LDS table; phase B gathers 10 rows simultaneously (6 lanes/row,
// ds_read_b128 of 8 bf16 features per lane). No shuffles in the j-loop.
#define ROWS_PER_CHUNK 10
#define WCAP 96   // per-row weight-slot capacity (max degree; binom(320,.1) ~ 32)
__global__ __launch_bounds__(256) void k_gat2(
    const float* __restrict__ h2, const float* __restrict__ es2,
    const float* __restrict__ ed2, const int* __restrict__ cols,
    const int* __restrict__ len, const float* __restrict__ p2w,
    float* __restrict__ part2) {
    int b = blockIdx.x >> 2, h = blockIdx.x & 3;
    int bh = b * H2C + h;
    __shared__ __align__(16) __hip_bfloat16 ht[NN * 48];   // 30720 B
    __shared__ float2 wtab[4][ROWS_PER_CHUNK * WCAP];      // 30720 B
    __shared__ float edl[NN];                              // 1280 B
    __shared__ int Ltab[4][ROWS_PER_CHUNK];                // 160 B
    int tid = threadIdx.x;
    // stage ht (fp32 -> bf16, row stride 48)
    const float2* hp2 = (const float2*)(h2 + (size_t)bh * NN * F2);
    for (int q = tid; q < NN * F2 / 2; q += 256) {
        int row = q / 23, c2 = (q - row * 23) * 2;
        float2 v = hp2[q];
        ht[row * 48 + c2]     = __float2bfloat16(v.x);
        ht[row * 48 + c2 + 1] = __float2bfloat16(v.y);
    }
    for (int t = tid; t < NN; t += 256) {
        *(unsigned*)&ht[t * 48 + 46] = 0u;                 // zero pad elems 46,47
        edl[t] = ed2[bh * NN + t];
    }
    __syncthreads();

    int wv = tid >> 6, lane = tid & 63;
    int g = lane / 6;                 // 0..10 (10 = idle lanes 60..63)
    int fl = lane - g * 6;
    bool gact = g < ROWS_PER_CHUNK;
    // per-lane pool weights for feature slice [fl*8, fl*8+8)
    float pw[8];
    #pragma unroll
    for (int k = 0; k < 8; ++k) {
        int f = fl * 8 + k;
        pw[k] = (gact && f < F2) ? p2w[h * F2 + f] : 0.f;
    }
    const char* hb = (const char*)ht;
    const float2* wrow = &wtab[wv][(gact ? g : 0) * WCAP];

    for (int c = 0; c < 8; ++c) {                          // 8 chunks x 10 rows
        int rowbase = wv * 80 + c * ROWS_PER_CHUNK;
        int Lmax = 0;
        // ---- phase A: weights for 10 rows ----
        for (int r = 0; r < ROWS_PER_CHUNK; ++r) {
            int i = rowbase + r;
            int L = len[i];
            float u = es2[bh * NN + i];
            if (L <= 64) {
                bool act = lane < L;
                int col = act ? cols[i * NN + lane] : 0;
                float e = -1e30f;
                if (act) {
                    float t = u + edl[col];
                    e = t > 0.f ? t : LRA * t;
                }
                float m = wave_max64(e);
                float w = act ? expf(e - m) : 0.f;
                float den = wave_sum64(w);
                float inv = 1.f / den;
                wtab[wv][r * WCAP + lane] =
                    make_float2(w * inv, __int_as_float(act ? col * 96 : 0));
            } else {                                       // generic fallback
                int Lc = L > WCAP ? WCAP : L;
                float m = -1e30f;
                for (int c0 = 0; c0 < Lc; c0 += 64) {
                    int idx = c0 + lane;
                    float e = -1e30f;
                    if (idx < Lc) {
                        float t = u + edl[cols[i * NN + idx]];
                        e = t > 0.f ? t : LRA * t;
                    }
                    m = fmaxf(m, wave_max64(e));
                }
                float den = 0.f;
                for (int c0 = 0; c0 < Lc; c0 += 64) {
                    int idx = c0 + lane;
                    float w = 0.f;
                    if (idx < Lc) {
                        float t = u + edl[cols[i * NN + idx]];
                        t = t > 0.f ? t : LRA * t;
                        w = expf(t - m);
                    }
                    den += wave_sum64(w);
                }
                float inv = 1.f / den;
                for (int c0 = 0; c0 < WCAP; c0 += 64) {
                    int idx = c0 + lane;
                    if (idx < WCAP) {
                        float w = 0.f;
                        int cc = 0;
                        if (idx < Lc) {
                            cc = cols[i * NN + idx];
                            float t = u + edl[cc];
                            t = t > 0.f ? t : LRA * t;
                            w = expf(t - m) * inv;
                        }
                        wtab[wv][r * WCAP + idx] =
                            make_float2(w, __int_as_float(cc * 96));
                    }
                }
                L = Lc;
            }
            if (lane == 0) Ltab[wv][r] = L;
            Lmax = Lmax > L ? Lmax : L;
        }
        // ---- phase B: gather-aggregate 10 rows together ----
        int Lg = gact ? Ltab[wv][g] : 0;
        float acc[8];
        #pragma unroll
        for (int k = 0; k < 8; ++k) acc[k] = 0.f;
        for (int j = 0; j < Lmax; ++j) {
            float2 p = wrow[j];
            bool on = j < Lg;
            float wn = on ? p.x : 0.f;
            int off = on ? __float_as_int(p.y) : 0;
            float4 q = *(const float4*)(hb + (off + fl * 16));
            int b0 = __float_as_int(q.x);
            int b1 = __float_as_int(q.y);
            int b2 = __float_as_int(q.z);
            int b3 = __float_as_int(q.w);
            acc[0] += wn * __int_as_float(b0 << 16);
            acc[1] += wn * __int_as_float(b0 & 0xffff0000);
            acc[2] += wn * __int_as_float(b1 << 16);
            acc[3] += wn * __int_as_float(b1 & 0xffff0000);
            acc[4] += wn * __int_as_float(b2 << 16);
            acc[5] += wn * __int_as_float(b2 & 0xffff0000);
            acc[6] += wn * __int_as_float(b3 << 16);
            acc[7] += wn * __int_as_float(b3 & 0xffff0000);
        }
        // ELU + pool partial
        float part = 0.f;
        #pragma unroll
        for (int k = 0; k < 8; ++k) {
            float v = acc[k];
            v = v > 0.f ? v : expm1f(v);
            part += v * pw[k];
        }
        // reduce across the 6 lanes of the group (original-value shuffles)
        part += __shfl_down(part, 3, 64);
        float t1 = __shfl_down(part, 1, 64);
        float t2 = __shfl_down(part, 2, 64);
        part = part + t1 + t2;
        if (gact && fl == 0) part2[bh * NN + rowbase + g] = part;
    }
}

// ---------------- K5: x2 combine + FC head ----------------
__global__ __launch_bounds__(128) void k_head(
    float* __restrict__ dout, const float* __restrict__ part2,
    const float* __restrict__ p2b, const float* __restrict__ e1w,
    const float* __restrict__ e1b, const float* __restrict__ e2w,
    const float* __restrict__ e2b, const float* __restrict__ e3w,
    const float* __restrict__ e3b, const float* __restrict__ cw,
    const float* __restrict__ cb) {
    int b = blockIdx.x;
    int tid = threadIdx.x;
    __shared__ float xc[960];
    __shared__ float h1[FC0];
    __shared__ float hh[FC1];
    __shared__ float ft[FC2];
    for (int t = tid; t < 640; t += 128) xc[t] = dout[b * 960 + t];
    for (int t = tid; t < NN; t += 128) {
        float s = p2b[0];
        #pragma unroll
        for (int h = 0; h < H2C; ++h) s += part2[(b * H2C + h) * NN + t];
        xc[640 + t] = s;
        dout[b * 960 + 640 + t] = s;
    }
    __syncthreads();
    if (tid < FC0) {
        float a = e1b[tid];
        for (int k = 0; k < 960; ++k) a += xc[k] * e1w[k * FC0 + tid];
        h1[tid] = a > 0.f ? a : expm1f(a);
    }
    __syncthreads();
    if (tid < FC1) {
        float a = e2b[tid];
        for (int k = 0; k < FC0; ++k) a += h1[k] * e2w[k * FC1 + tid];
        hh[tid] = a > 0.f ? a : expm1f(a);
    }
    __syncthreads();
    if (tid < FC2) {
        float a = e3b[tid];
        for (int k = 0; k < FC1; ++k) a += hh[k] * e3w[k * FC2 + tid];
        a = a > 0.f ? a : expm1f(a);
        ft[tid] = a;
        dout[BS * 960 + b * FC2 + tid] = a;
    }
    __syncthreads();
    if (tid < 64) {
        float v = 0.f;
        for (int t = tid; t < FC2; t += 64) v += ft[t] * cw[t];
        v = wave_sum64(v);
        if (tid == 0) dout[BS * 960 + BS * FC2 + b] = v + cb[0];
    }
}

extern "C" void kernel_launch(void* const* d_in, const int* in_sizes, int n_in,
                              void* d_out, int out_size, void* d_ws,
                              size_t ws_size, hipStream_t stream) {
    const float* xn  = (const float*)d_in[0];
    const float* adj = (const float*)d_in[1];
    const float* W1  = (const float*)d_in[2];
    const float* a1  = (const float*)d_in[3];
    const float* W2  = (const float*)d_in[4];
    const float* a2  = (const float*)d_in[5];
    const float* p1w = (const float*)d_in[6];
    const float* p1b = (const float*)d_in[7];
    const float* p2w = (const float*)d_in[8];
    const float* p2b = (const float*)d_in[9];
    const float* e1w = (const float*)d_in[10];
    const float* e1b = (const float*)d_in[11];
    const float* e2w = (const float*)d_in[12];
    const float* e2b = (const float*)d_in[13];
    const float* e3w = (const float*)d_in[14];
    const float* e3b = (const float*)d_in[15];
    const float* cw  = (const float*)d_in[16];
    const float* cb  = (const float*)d_in[17];

    char* ws = (char*)d_ws;
    int*   csr_len  = (int*)ws;                       // 1280 B
    float* c1s      = (float*)(ws + 1280);            // 32 B
    float* c1d      = (float*)(ws + 1312);            // 32 B (pad to 1536)
    int*   csr_cols = (int*)(ws + 1536);              // 409600 -> 411136
    float* out1     = (float*)(ws + 411136);          // 23592960 -> 24004096
    float* h2       = (float*)(ws + 24004096);        // 30146560 -> 54150656
    float* es2      = (float*)(ws + 54150656);        // 655360 -> 54806016
    float* ed2      = (float*)(ws + 54806016);        // 655360 -> 55461376
    float* part2    = (float*)(ws + 55461376);        // 655360 -> 56116736
    float* dout     = (float*)d_out;

    k_csr<<<NN + 1, 64, 0, stream>>>(adj, csr_cols, csr_len, W1, a1, c1s, c1d);
    k_gat1<<<BS * H1, 256, 0, stream>>>(xn, csr_cols, csr_len, W1, c1s, c1d, out1);
    k_pool1<<<(BS * NN + 255) / 256, 256, 0, stream>>>(out1, xn, p1w, p1b, dout);
    k_gemm2<<<BS * NN / 64, 128, 0, stream>>>(out1, W2, a2, h2, es2, ed2);
    k_gat2<<<BS * H2C, 256, 0, stream>>>(h2, es2, ed2, csr_cols, csr_len, p2w, part2);
    k_head<<<BS, 128, 0, stream>>>(dout, part2, p2b, e1w, e1b, e2w, e2b, e3w, e3b, cw, cb);
}

// Round 3
// 367.117 us; speedup vs baseline: 1.8218x; 1.3021x over previous
//
#include <hip/hip_runtime.h>
#include <hip/hip_bf16.h>
#include <math.h>

#define BS 128
#define NN 320
#define H1 8
#define F1 18
#define D1 144
#define H2C 4
#define F2 46
#define FC0 104
#define FC1 45
#define FC2 84
#define LRA 0.2f

typedef __attribute__((ext_vector_type(8))) short bf16x8;
typedef __attribute__((ext_vector_type(4))) float f32x4;

__device__ __forceinline__ float wave_max64(float v) {
    #pragma unroll
    for (int off = 32; off > 0; off >>= 1)
        v = fmaxf(v, __shfl_xor(v, off, 64));
    return v;
}
__device__ __forceinline__ float wave_sum64(float v) {
    #pragma unroll
    for (int off = 32; off > 0; off >>= 1)
        v += __shfl_xor(v, off, 64);
    return v;
}

// ---- K0: CSR build + layer-1 constants + bf16 B-matrix pack ----------------
// blocks 0..319: CSR rows; block 320: c1s/c1d; blocks 321..800: Bb pack.
__global__ void k_csr(const float* __restrict__ adj, int* __restrict__ cols,
                      int* __restrict__ len, const float* __restrict__ W1,
                      const float* __restrict__ a1, float* __restrict__ c1s,
                      float* __restrict__ c1d, const float* __restrict__ W2,
                      __hip_bfloat16* __restrict__ Bb) {
    int row = blockIdx.x;
    int lane = threadIdx.x;  // 64 threads
    if (row < NN) {
        int base = 0;
        for (int c0 = 0; c0 < NN; c0 += 64) {
            int j = c0 + lane;
            bool p = (j < NN) && (adj[row * NN + j] > 0.f);
            unsigned long long m = __ballot(p);
            if (p) {
                int pos = base + __popcll(m & ((1ull << lane) - 1ull));
                cols[row * NN + pos] = j;
            }
            base += __popcll(m);
        }
        if (lane == 0) len[row] = base;
    } else if (row == NN) {
        int h = lane;
        if (h < H1) {
            float s = 0.f, d = 0.f;
            for (int f = 0; f < F1; ++f) {
                float w = W1[h * F1 + f];
                s += w * a1[h * 2 * F1 + f];
                d += w * a1[h * 2 * F1 + F1 + f];
            }
            c1s[h] = s;
            c1d[h] = d;
        }
    } else {
        // Bb[k8][n][e]: element idx = (k8*192 + n)*8 + e, k = k8*8+e, n = h*48+f
        int idx = (row - NN - 1) * 64 + lane;   // 0..30719
        int e = idx & 7;
        int t = idx >> 3;
        int n = t % 192, k8 = t / 192;
        int k = k8 * 8 + e, hh = n / 48, f = n - hh * 48;
        float v = (k < 144 && f < 46) ? W2[(hh * 144 + k) * 46 + f] : 0.f;
        Bb[idx] = __float2bfloat16(v);
    }
}

// ---- K1: layer-1 GAT (rank-1) -> bf16 out1 [.][160] + pool1 partials -------
__global__ __launch_bounds__(256) void k_gat1(
    const float* __restrict__ xn, const int* __restrict__ cols,
    const int* __restrict__ len, const float* __restrict__ W1,
    const float* __restrict__ c1s, const float* __restrict__ c1d,
    const float* __restrict__ p1w, __hip_bfloat16* __restrict__ out1b,
    float* __restrict__ part1) {
    int b = blockIdx.x >> 3;
    int h = blockIdx.x & 7;
    __shared__ float xb[NN];
    __shared__ float w1h[F1], pwl[F1];
    int tid = threadIdx.x;
    for (int t = tid; t < NN; t += 256) xb[t] = xn[b * NN + t];
    if (tid < F1) { w1h[tid] = W1[h * F1 + tid]; pwl[tid] = p1w[h * F1 + tid]; }
    __syncthreads();
    float cs = c1s[h], cd = c1d[h];
    int wave = tid >> 6, lane = tid & 63;
    for (int i = wave; i < NN; i += 4) {
        float u = xb[i] * cs;
        int L = len[i];
        float s;
        if (L <= 64) {
            bool act = lane < L;
            int col = act ? cols[i * NN + lane] : 0;
            float xc = act ? xb[col] : 0.f;
            float t = u + xc * cd;
            t = t > 0.f ? t : LRA * t;
            float e = act ? t : -1e30f;
            float m = wave_max64(e);
            float w = act ? expf(e - m) : 0.f;
            float den = wave_sum64(w);
            float num = wave_sum64(w * xc);
            s = num / den;
        } else {
            float m = -1e30f;
            for (int c0 = 0; c0 < L; c0 += 64) {
                int idx = c0 + lane;
                float e = -1e30f;
                if (idx < L) {
                    float t = u + xb[cols[i * NN + idx]] * cd;
                    e = t > 0.f ? t : LRA * t;
                }
                m = fmaxf(m, wave_max64(e));
            }
            float den = 0.f, num = 0.f;
            for (int c0 = 0; c0 < L; c0 += 64) {
                int idx = c0 + lane;
                float w = 0.f, wx = 0.f;
                if (idx < L) {
                    float xc = xb[cols[i * NN + idx]];
                    float t = u + xc * cd;
                    t = t > 0.f ? t : LRA * t;
                    w = expf(t - m);
                    wx = w * xc;
                }
                den += wave_sum64(w);
                num += wave_sum64(wx);
            }
            s = num / den;
        }
        float pv = 0.f;
        size_t rbase = (size_t)(b * NN + i) * 160;
        if (lane < F1) {
            float v = s * w1h[lane];
            v = v > 0.f ? v : expm1f(v);
            pv = v * pwl[lane];
            out1b[rbase + h * F1 + lane] = __float2bfloat16(v);
        } else if (h == 7 && lane < F1 + 16) {
            out1b[rbase + 144 + (lane - F1)] = __float2bfloat16(0.f);
        }
        float ps = wave_sum64(pv);
        if (lane == 0) part1[(b * 8 + h) * NN + i] = ps;
    }
}

// ---- K3: h2 = out1 @ W2 via bf16 MFMA --------------------------------------
// block: 64 rows x 96 cols (hblk selects N-half). 256 thr = 4 waves x 16 rows.
__global__ __launch_bounds__(256) void k_gemm2(
    const __hip_bfloat16* __restrict__ A,    // [40960][160] bf16
    const __hip_bfloat16* __restrict__ Bb,   // [20][192][8] bf16
    __hip_bfloat16* __restrict__ h2b) {      // per bh: [320][48] bf16
    __shared__ __align__(16) __hip_bfloat16 As[64 * 168];   // 21504 B
    __shared__ __align__(16) __hip_bfloat16 Bs[20 * 96 * 8]; // 30720 B
    int tid = threadIdx.x;
    int mblk = blockIdx.x >> 1, hblk = blockIdx.x & 1;
    int r0 = mblk * 64;
    const uint4* Ag = (const uint4*)(A + (size_t)r0 * 160);
    for (int q = tid; q < 1280; q += 256) {
        int row = q / 20, k8 = q % 20;
        *(uint4*)(As + row * 168 + k8 * 8) = Ag[q];
    }
    const uint4* Bg = (const uint4*)Bb;
    for (int q = tid; q < 1920; q += 256) {
        int k8 = q / 96, nl = q % 96;
        *(uint4*)(Bs + (k8 * 96 + nl) * 8) = Bg[k8 * 192 + hblk * 96 + nl];
    }
    __syncthreads();
    int wv = tid >> 6, l = tid & 63;
    int lr = l & 15, lq = l >> 4;
    bf16x8 af[5];
    const __hip_bfloat16* arow = As + (wv * 16 + lr) * 168 + lq * 8;
    #pragma unroll
    for (int kc = 0; kc < 5; ++kc)
        af[kc] = *(const bf16x8*)(arow + kc * 32);
    f32x4 acc[6];
    #pragma unroll
    for (int t = 0; t < 6; ++t) acc[t] = (f32x4){0.f, 0.f, 0.f, 0.f};
    #pragma unroll
    for (int t = 0; t < 6; ++t) {
        const __hip_bfloat16* bcol = Bs + (t * 16 + lr) * 8;
        #pragma unroll
        for (int kc = 0; kc < 5; ++kc) {
            bf16x8 bf = *(const bf16x8*)(bcol + (kc * 4 + lq) * 768);
            acc[t] = __builtin_amdgcn_mfma_f32_16x16x32_bf16(af[kc], bf, acc[t], 0, 0, 0);
        }
    }
    #pragma unroll
    for (int t = 0; t < 6; ++t) {
        int c = hblk * 96 + t * 16 + lr;
        int hh = c / 48, f = c - hh * 48;
        int rowb = r0 + wv * 16 + lq * 4;
        #pragma unroll
        for (int j = 0; j < 4; ++j) {
            int row = rowb + j;
            int b = row / 320, n = row - b * 320;
            h2b[((size_t)(b * 4 + hh) * 320 + n) * 48 + f] =
                __float2bfloat16(acc[t][j]);
        }
    }
}

// ---- K4: layer-2 GAT attention + fused pool2 partials ----------------------
#define RPC 10
#define WCAP 96
__global__ __launch_bounds__(256) void k_gat2(
    const __hip_bfloat16* __restrict__ h2b, const float* __restrict__ a2,
    const int* __restrict__ cols, const int* __restrict__ len,
    const float* __restrict__ p2w, float* __restrict__ part2) {
    int b = blockIdx.x >> 2, h = blockIdx.x & 3;
    int bh = b * 4 + h;
    __shared__ __align__(16) __hip_bfloat16 ht[NN * 48];   // 30720 B
    __shared__ float2 wtab[4][RPC * WCAP];                 // 30720 B
    __shared__ float edl[NN], esl[NN];                     // 2560 B
    __shared__ float a2e[48], a2d[48];                     // 384 B
    __shared__ int Ltab[4][RPC];                           // 160 B
    int tid = threadIdx.x;
    const uint4* hp = (const uint4*)(h2b + (size_t)bh * NN * 48);
    for (int q = tid; q < NN * 48 / 8; q += 256) ((uint4*)ht)[q] = hp[q];
    if (tid < 48) {
        a2e[tid] = tid < 46 ? a2[h * 92 + tid] : 0.f;
        a2d[tid] = tid < 46 ? a2[h * 92 + 46 + tid] : 0.f;
    }
    __syncthreads();
    for (int i = tid; i < NN; i += 256) {
        const uint4* hr = (const uint4*)(ht + i * 48);
        float es = 0.f, ed = 0.f;
        #pragma unroll
        for (int u = 0; u < 6; ++u) {
            uint4 w = hr[u];
            unsigned ww[4] = {w.x, w.y, w.z, w.w};
            #pragma unroll
            for (int z = 0; z < 4; ++z) {
                float lo = __int_as_float((int)(ww[z] << 16));
                float hi = __int_as_float((int)(ww[z] & 0xffff0000u));
                int f = u * 8 + z * 2;
                es += lo * a2e[f] + hi * a2e[f + 1];
                ed += lo * a2d[f] + hi * a2d[f + 1];
            }
        }
        esl[i] = es;
        edl[i] = ed;
    }
    __syncthreads();

    int wv = tid >> 6, lane = tid & 63;
    int g = lane / 6;
    int fl = lane - g * 6;
    bool gact = g < RPC;
    float pw[8];
    #pragma unroll
    for (int k = 0; k < 8; ++k) {
        int f = fl * 8 + k;
        pw[k] = (gact && f < F2) ? p2w[h * F2 + f] : 0.f;
    }
    const char* hb = (const char*)ht;
    const float2* wrow = &wtab[wv][(gact ? g : 0) * WCAP];

    for (int c = 0; c < 8; ++c) {
        int rowbase = wv * 80 + c * RPC;
        int Lmax = 0;
        for (int r = 0; r < RPC; ++r) {
            int i = rowbase + r;
            int L = len[i];
            float u = esl[i];
            if (L <= 64) {
                bool act = lane < L;
                int col = act ? cols[i * NN + lane] : 0;
                float e = -1e30f;
                if (act) {
                    float t = u + edl[col];
                    e = t > 0.f ? t : LRA * t;
                }
                float m = wave_max64(e);
                float w = act ? expf(e - m) : 0.f;
                float den = wave_sum64(w);
                float inv = 1.f / den;
                wtab[wv][r * WCAP + lane] =
                    make_float2(w * inv, __int_as_float(act ? col * 96 : 0));
            } else {
                int Lc = L > WCAP ? WCAP : L;
                float m = -1e30f;
                for (int c0 = 0; c0 < Lc; c0 += 64) {
                    int idx = c0 + lane;
                    float e = -1e30f;
                    if (idx < Lc) {
                        float t = u + edl[cols[i * NN + idx]];
                        e = t > 0.f ? t : LRA * t;
                    }
                    m = fmaxf(m, wave_max64(e));
                }
                float den = 0.f;
                for (int c0 = 0; c0 < Lc; c0 += 64) {
                    int idx = c0 + lane;
                    float w = 0.f;
                    if (idx < Lc) {
                        float t = u + edl[cols[i * NN + idx]];
                        t = t > 0.f ? t : LRA * t;
                        w = expf(t - m);
                    }
                    den += wave_sum64(w);
                }
                float inv = 1.f / den;
                for (int c0 = 0; c0 < WCAP; c0 += 64) {
                    int idx = c0 + lane;
                    if (idx < WCAP) {
                        float w = 0.f;
                        int cc = 0;
                        if (idx < Lc) {
                            cc = cols[i * NN + idx];
                            float t = u + edl[cc];
                            t = t > 0.f ? t : LRA * t;
                            w = expf(t - m) * inv;
                        }
                        wtab[wv][r * WCAP + idx] =
                            make_float2(w, __int_as_float(cc * 96));
                    }
                }
                L = Lc;
            }
            if (lane == 0) Ltab[wv][r] = L;
            Lmax = Lmax > L ? Lmax : L;
        }
        int Lg = gact ? Ltab[wv][g] : 0;
        float acc[8];
        #pragma unroll
        for (int k = 0; k < 8; ++k) acc[k] = 0.f;
        for (int j = 0; j < Lmax; ++j) {
            float2 p = wrow[j];
            bool on = j < Lg;
            float wn = on ? p.x : 0.f;
            int off = on ? __float_as_int(p.y) : 0;
            float4 q = *(const float4*)(hb + (off + fl * 16));
            int b0 = __float_as_int(q.x);
            int b1 = __float_as_int(q.y);
            int b2 = __float_as_int(q.z);
            int b3 = __float_as_int(q.w);
            acc[0] += wn * __int_as_float(b0 << 16);
            acc[1] += wn * __int_as_float(b0 & 0xffff0000);
            acc[2] += wn * __int_as_float(b1 << 16);
            acc[3] += wn * __int_as_float(b1 & 0xffff0000);
            acc[4] += wn * __int_as_float(b2 << 16);
            acc[5] += wn * __int_as_float(b2 & 0xffff0000);
            acc[6] += wn * __int_as_float(b3 << 16);
            acc[7] += wn * __int_as_float(b3 & 0xffff0000);
        }
        float part = 0.f;
        #pragma unroll
        for (int k = 0; k < 8; ++k) {
            float v = acc[k];
            v = v > 0.f ? v : expm1f(v);
            part += v * pw[k];
        }
        part += __shfl_down(part, 3, 64);
        float t1 = __shfl_down(part, 1, 64);
        float t2 = __shfl_down(part, 2, 64);
        part = part + t1 + t2;
        if (gact && fl == 0) part2[bh * NN + rowbase + g] = part;
    }
}

// ---- K5: x_concat assembly + FC head ---------------------------------------
__global__ __launch_bounds__(128) void k_head(
    const float* __restrict__ xn, const float* __restrict__ part1,
    const float* __restrict__ part2, const float* __restrict__ p1b,
    const float* __restrict__ p2b, const float* __restrict__ e1w,
    const float* __restrict__ e1b, const float* __restrict__ e2w,
    const float* __restrict__ e2b, const float* __restrict__ e3w,
    const float* __restrict__ e3b, const float* __restrict__ cw,
    const float* __restrict__ cb, float* __restrict__ dout) {
    int b = blockIdx.x;
    int tid = threadIdx.x;
    __shared__ float xc[960];
    __shared__ float h1[FC0];
    __shared__ float hh[FC1];
    __shared__ float ft[FC2];
    for (int t = tid; t < NN; t += 128) {
        float x0 = xn[b * NN + t];
        xc[t] = x0;
        dout[b * 960 + t] = x0;
        float s1 = p1b[0];
        #pragma unroll
        for (int h = 0; h < 8; ++h) s1 += part1[(b * 8 + h) * NN + t];
        xc[320 + t] = s1;
        dout[b * 960 + 320 + t] = s1;
        float s2 = p2b[0];
        #pragma unroll
        for (int h = 0; h < 4; ++h) s2 += part2[(b * 4 + h) * NN + t];
        xc[640 + t] = s2;
        dout[b * 960 + 640 + t] = s2;
    }
    __syncthreads();
    if (tid < FC0) {
        float a = e1b[tid];
        for (int k = 0; k < 960; ++k) a += xc[k] * e1w[k * FC0 + tid];
        h1[tid] = a > 0.f ? a : expm1f(a);
    }
    __syncthreads();
    if (tid < FC1) {
        float a = e2b[tid];
        for (int k = 0; k < FC0; ++k) a += h1[k] * e2w[k * FC1 + tid];
        hh[tid] = a > 0.f ? a : expm1f(a);
    }
    __syncthreads();
    if (tid < FC2) {
        float a = e3b[tid];
        for (int k = 0; k < FC1; ++k) a += hh[k] * e3w[k * FC2 + tid];
        a = a > 0.f ? a : expm1f(a);
        ft[tid] = a;
        dout[BS * 960 + b * FC2 + tid] = a;
    }
    __syncthreads();
    if (tid < 64) {
        float v = 0.f;
        for (int t = tid; t < FC2; t += 64) v += ft[t] * cw[t];
        v = wave_sum64(v);
        if (tid == 0) dout[BS * 960 + BS * FC2 + b] = v + cb[0];
    }
}

extern "C" void kernel_launch(void* const* d_in, const int* in_sizes, int n_in,
                              void* d_out, int out_size, void* d_ws,
                              size_t ws_size, hipStream_t stream) {
    const float* xn  = (const float*)d_in[0];
    const float* adj = (const float*)d_in[1];
    const float* W1  = (const float*)d_in[2];
    const float* a1  = (const float*)d_in[3];
    const float* W2  = (const float*)d_in[4];
    const float* a2  = (const float*)d_in[5];
    const float* p1w = (const float*)d_in[6];
    const float* p1b = (const float*)d_in[7];
    const float* p2w = (const float*)d_in[8];
    const float* p2b = (const float*)d_in[9];
    const float* e1w = (const float*)d_in[10];
    const float* e1b = (const float*)d_in[11];
    const float* e2w = (const float*)d_in[12];
    const float* e2b = (const float*)d_in[13];
    const float* e3w = (const float*)d_in[14];
    const float* e3b = (const float*)d_in[15];
    const float* cw  = (const float*)d_in[16];
    const float* cb  = (const float*)d_in[17];

    char* ws = (char*)d_ws;
    int*   csr_len  = (int*)ws;                            // 1280
    float* c1s      = (float*)(ws + 1280);                 // 32
    float* c1d      = (float*)(ws + 1312);                 // 32 (pad->1536)
    int*   csr_cols = (int*)(ws + 1536);                   // 409600 -> 411136
    __hip_bfloat16* out1b = (__hip_bfloat16*)(ws + 411136);    // 13107200 -> 13518336
    __hip_bfloat16* Bb    = (__hip_bfloat16*)(ws + 13518336);  // 61440 -> 13579776
    __hip_bfloat16* h2b   = (__hip_bfloat16*)(ws + 13579776);  // 15728640 -> 29308416
    float* part1    = (float*)(ws + 29308416);             // 1310720 -> 30619136
    float* part2    = (float*)(ws + 30619136);             // 655360 -> 31274496
    float* dout     = (float*)d_out;

    k_csr<<<NN + 1 + 480, 64, 0, stream>>>(adj, csr_cols, csr_len, W1, a1,
                                           c1s, c1d, W2, Bb);
    k_gat1<<<BS * H1, 256, 0, stream>>>(xn, csr_cols, csr_len, W1, c1s, c1d,
                                        p1w, out1b, part1);
    k_gemm2<<<(BS * NN / 64) * 2, 256, 0, stream>>>(out1b, Bb, h2b);
    k_gat2<<<BS * H2C, 256, 0, stream>>>(h2b, a2, csr_cols, csr_len, p2w, part2);
    k_head<<<BS, 128, 0, stream>>>(xn, part1, part2, p1b, p2b, e1w, e1b,
                                   e2w, e2b, e3w, e3b, cw, cb, dout);
}

// Round 4
// 230.609 us; speedup vs baseline: 2.9001x; 1.5919x over previous
//
#include <hip/hip_runtime.h>
#include <hip/hip_bf16.h>
#include <math.h>

#define BS 128
#define NN 320
#define H1 8
#define F1 18
#define D1 144
#define H2C 4
#define F2 46
#define FC0 104
#define FC1 45
#define FC2 84
#define LRA 0.2f
#define DEGCAP 96
#define HST 56   // ht row stride in bf16 (112 B, 16B-aligned, 28 dwords)

typedef __attribute__((ext_vector_type(8))) short bf16x8;
typedef __attribute__((ext_vector_type(4))) float f32x4;

__device__ __forceinline__ float wave_max64(float v) {
    #pragma unroll
    for (int off = 32; off > 0; off >>= 1)
        v = fmaxf(v, __shfl_xor(v, off, 64));
    return v;
}
__device__ __forceinline__ float wave_sum64(float v) {
    #pragma unroll
    for (int off = 32; off > 0; off >>= 1)
        v += __shfl_xor(v, off, 64);
    return v;
}

// ---- K0: CSR build (u16, fwd + transposed) + l1 consts + Bb pack -----------
__global__ void k_csr(const float* __restrict__ adj,
                      unsigned short* __restrict__ cols16,
                      unsigned short* __restrict__ colsT16,
                      int* __restrict__ len, const float* __restrict__ W1,
                      const float* __restrict__ a1, float* __restrict__ c1s,
                      float* __restrict__ c1d, const float* __restrict__ W2,
                      __hip_bfloat16* __restrict__ Bb) {
    int row = blockIdx.x;
    int lane = threadIdx.x;  // 64 threads
    if (row < NN) {
        int base = 0;
        for (int c0 = 0; c0 < NN; c0 += 64) {
            int j = c0 + lane;
            bool p = (j < NN) && (adj[row * NN + j] > 0.f);
            unsigned long long m = __ballot(p);
            if (p) {
                int pos = base + __popcll(m & ((1ull << lane) - 1ull));
                if (pos < DEGCAP) {
                    cols16[row * DEGCAP + pos] = (unsigned short)j;
                    colsT16[pos * NN + row] = (unsigned short)j;
                }
            }
            base += __popcll(m);
        }
        if (base > DEGCAP) base = DEGCAP;
        for (int q = base + lane; q < DEGCAP; q += 64) {
            cols16[row * DEGCAP + q] = 0;
            colsT16[q * NN + row] = 0;
        }
        if (lane == 0) len[row] = base;
    } else if (row == NN) {
        int h = lane;
        if (h < H1) {
            float s = 0.f, d = 0.f;
            for (int f = 0; f < F1; ++f) {
                float w = W1[h * F1 + f];
                s += w * a1[h * 2 * F1 + f];
                d += w * a1[h * 2 * F1 + F1 + f];
            }
            c1s[h] = s;
            c1d[h] = d;
        }
    } else {
        // Bb[k8][n][e]: n = h*48+f; zero pad cols f>=46 and k>=144
        int idx = (row - NN - 1) * 64 + lane;   // 0..30719
        int e = idx & 7;
        int t = idx >> 3;
        int n = t % 192, k8 = t / 192;
        int k = k8 * 8 + e, hh = n / 48, f = n - hh * 48;
        float v = (k < 144 && f < 46) ? W2[(hh * 144 + k) * 46 + f] : 0.f;
        Bb[idx] = __float2bfloat16(v);
    }
}

// ---- K1: layer-1 GAT, lanes=rows ------------------------------------------
// grid (b, hg): 256 blocks, 320 threads (= NN). Each lane owns row tid,
// handles 4 heads hg*4..hg*4+3. No per-row reductions: softmax shift from
// global max/min of x (lrelu monotone).
__global__ __launch_bounds__(320) void k_gat1(
    const float* __restrict__ xn, const unsigned short* __restrict__ colsT16,
    const int* __restrict__ len, const float* __restrict__ W1,
    const float* __restrict__ c1s, const float* __restrict__ c1d,
    const float* __restrict__ p1w, __hip_bfloat16* __restrict__ out1b,
    float* __restrict__ part1) {
    int b = blockIdx.x >> 1, hg = blockIdx.x & 1;
    __shared__ float xb[NN];
    __shared__ float stab[4][NN];
    __shared__ float w1h[4][F1], pwl[4][F1];
    __shared__ float redmax[5], redmin[5];
    int tid = threadIdx.x;          // == row
    int wv = tid >> 6, lane = tid & 63;
    float xi = xn[b * NN + tid];
    xb[tid] = xi;
    if (tid < 72) {
        int hh = tid / F1, f = tid - hh * F1;
        w1h[hh][f] = W1[(hg * 4 + hh) * F1 + f];
        pwl[hh][f] = p1w[(hg * 4 + hh) * F1 + f];
    }
    int Li = len[tid];
    float mx = wave_max64(xi);
    float mn = -wave_max64(-xi);
    int Lmax = (int)wave_max64((float)Li);
    if (lane == 0) { redmax[wv] = mx; redmin[wv] = mn; }
    __syncthreads();
    float MX = redmax[0], MN = redmin[0];
    #pragma unroll
    for (int q = 1; q < 5; ++q) {
        MX = fmaxf(MX, redmax[q]);
        MN = fminf(MN, redmin[q]);
    }
    float u[4], m[4], num[4], den[4], cd[4];
    #pragma unroll
    for (int hh = 0; hh < 4; ++hh) {
        float cs = c1s[hg * 4 + hh];
        cd[hh] = c1d[hg * 4 + hh];
        u[hh] = xi * cs;
        float mt = u[hh] + (cd[hh] > 0.f ? cd[hh] * MX : cd[hh] * MN);
        m[hh] = fmaxf(mt, LRA * mt);
        num[hh] = 0.f; den[hh] = 0.f;
    }
    const unsigned short* ct = colsT16 + tid;
    int colv = ct[0];
    for (int j = 0; j < Lmax; ++j) {
        int coln = (j + 1 < Lmax) ? ct[(j + 1) * NN] : 0;
        float xj = xb[colv];
        bool act = j < Li;
        #pragma unroll
        for (int hh = 0; hh < 4; ++hh) {
            float t = fmaf(xj, cd[hh], u[hh]);
            t = fmaxf(t, LRA * t);
            float w = __expf(t - m[hh]);
            w = act ? w : 0.f;
            num[hh] = fmaf(w, xj, num[hh]);
            den[hh] += w;
        }
        colv = coln;
    }
    #pragma unroll
    for (int hh = 0; hh < 4; ++hh) stab[hh][tid] = num[hh] / den[hh];
    __syncthreads();
    // write phase (coalesced bf16 stores); hg==1 also writes pad cols 144..159
    if (hg == 0) {
        for (int idx = tid; idx < NN * 72; idx += 320) {
            int row = idx / 72, c = idx - row * 72;
            int hh = c / F1, f = c - hh * F1;
            float v = stab[hh][row] * w1h[hh][f];
            v = v > 0.f ? v : expm1f(v);
            out1b[(size_t)(b * NN + row) * 160 + c] = __float2bfloat16(v);
        }
    } else {
        for (int idx = tid; idx < NN * 88; idx += 320) {
            int row = idx / 88, c = idx - row * 88;
            float v = 0.f;
            if (c < 72) {
                int hh = c / F1, f = c - hh * F1;
                v = stab[hh][row] * w1h[hh][f];
                v = v > 0.f ? v : expm1f(v);
            }
            out1b[(size_t)(b * NN + row) * 160 + 72 + c] = __float2bfloat16(v);
        }
    }
    // pool phase: lanes=rows
    float part = 0.f;
    #pragma unroll
    for (int hh = 0; hh < 4; ++hh) {
        float s = stab[hh][tid];
        #pragma unroll
        for (int f = 0; f < F1; ++f) {
            float v = s * w1h[hh][f];
            v = v > 0.f ? v : expm1f(v);
            part = fmaf(v, pwl[hh][f], part);
        }
    }
    part1[(size_t)(b * 2 + hg) * NN + tid] = part;
}

// ---- K3: h2 = out1 @ W2 via bf16 MFMA (out stride HST=56) ------------------
__global__ __launch_bounds__(256) void k_gemm2(
    const __hip_bfloat16* __restrict__ A,    // [40960][160] bf16
    const __hip_bfloat16* __restrict__ Bb,   // [20][192][8] bf16
    __hip_bfloat16* __restrict__ h2b) {      // per bh: [320][HST] bf16
    __shared__ __align__(16) __hip_bfloat16 As[64 * 168];
    __shared__ __align__(16) __hip_bfloat16 Bs[20 * 96 * 8];
    int tid = threadIdx.x;
    int mblk = blockIdx.x >> 1, hblk = blockIdx.x & 1;
    int r0 = mblk * 64;
    const uint4* Ag = (const uint4*)(A + (size_t)r0 * 160);
    for (int q = tid; q < 1280; q += 256) {
        int row = q / 20, k8 = q % 20;
        *(uint4*)(As + row * 168 + k8 * 8) = Ag[q];
    }
    const uint4* Bg = (const uint4*)Bb;
    for (int q = tid; q < 1920; q += 256) {
        int k8 = q / 96, nl = q % 96;
        *(uint4*)(Bs + (k8 * 96 + nl) * 8) = Bg[k8 * 192 + hblk * 96 + nl];
    }
    __syncthreads();
    int wv = tid >> 6, l = tid & 63;
    int lr = l & 15, lq = l >> 4;
    bf16x8 af[5];
    const __hip_bfloat16* arow = As + (wv * 16 + lr) * 168 + lq * 8;
    #pragma unroll
    for (int kc = 0; kc < 5; ++kc)
        af[kc] = *(const bf16x8*)(arow + kc * 32);
    f32x4 acc[6];
    #pragma unroll
    for (int t = 0; t < 6; ++t) acc[t] = (f32x4){0.f, 0.f, 0.f, 0.f};
    #pragma unroll
    for (int t = 0; t < 6; ++t) {
        const __hip_bfloat16* bcol = Bs + (t * 16 + lr) * 8;
        #pragma unroll
        for (int kc = 0; kc < 5; ++kc) {
            bf16x8 bf = *(const bf16x8*)(bcol + (kc * 4 + lq) * 768);
            acc[t] = __builtin_amdgcn_mfma_f32_16x16x32_bf16(af[kc], bf, acc[t], 0, 0, 0);
        }
    }
    #pragma unroll
    for (int t = 0; t < 6; ++t) {
        int c = hblk * 96 + t * 16 + lr;
        int hh = c / 48, f = c - hh * 48;
        int rowb = r0 + wv * 16 + lq * 4;
        #pragma unroll
        for (int j = 0; j < 4; ++j) {
            int row = rowb + j;
            int b = row / 320, n = row - b * 320;
            h2b[((size_t)(b * 4 + hh) * 320 + n) * HST + f] =
                __float2bfloat16(acc[t][j]);
        }
    }
}

// ---- K4: layer-2 GAT, single-pass (no phase A, no wtab) --------------------
// grid (bh, rhalf): 1024 blocks, 256 thr. 10 groups x 6 lanes per wave; per
// group-row: loop neighbors, w = exp(lrelu(es+ed)-m) with m from global max
// of ed (lrelu monotone); aggregate unnormalized, divide at end.
__global__ __launch_bounds__(256) void k_gat2(
    const __hip_bfloat16* __restrict__ h2b, const float* __restrict__ a2,
    const unsigned short* __restrict__ cols16, const int* __restrict__ len,
    const float* __restrict__ p2w, float* __restrict__ part2) {
    int bh = blockIdx.x >> 1, rh = blockIdx.x & 1;
    int h = bh & 3;
    __shared__ __align__(16) __hip_bfloat16 ht[NN * HST];  // 35840 B
    __shared__ float esl[NN], edl[NN];                     // 2560 B
    __shared__ int lenl[NN];                               // 1280 B
    __shared__ float a2e[48], a2d[48];                     // 384 B
    __shared__ float Mred[4];
    int tid = threadIdx.x;
    const uint4* hp = (const uint4*)(h2b + (size_t)bh * NN * HST);
    for (int q = tid; q < NN * HST / 8; q += 256) ((uint4*)ht)[q] = hp[q];
    if (tid < 48) {
        a2e[tid] = tid < 46 ? a2[h * 92 + tid] : 0.f;
        a2d[tid] = tid < 46 ? a2[h * 92 + 46 + tid] : 0.f;
    }
    for (int t = tid; t < NN; t += 256) lenl[t] = len[t];
    __syncthreads();
    float edmax = -1e30f;
    for (int i2 = tid; i2 < NN; i2 += 256) {
        const unsigned* hr = (const unsigned*)(ht + i2 * HST);
        float es = 0.f, ed = 0.f;
        #pragma unroll
        for (int z = 0; z < 24; ++z) {
            unsigned w = hr[z];
            float lo = __int_as_float((int)(w << 16));
            float hi = __int_as_float((int)(w & 0xffff0000u));
            es += lo * a2e[2 * z] + hi * a2e[2 * z + 1];
            ed += lo * a2d[2 * z] + hi * a2d[2 * z + 1];
        }
        esl[i2] = es;
        edl[i2] = ed;
        edmax = fmaxf(edmax, ed);
    }
    int wv = tid >> 6, lane = tid & 63;
    float wm = wave_max64(edmax);
    if (lane == 0) Mred[wv] = wm;
    __syncthreads();
    float M = fmaxf(fmaxf(Mred[0], Mred[1]), fmaxf(Mred[2], Mred[3]));
    int g = lane / 6;
    int fl = lane - g * 6;
    bool gact = g < 10;
    int geff = gact ? g : 0;
    float pw[8];
    #pragma unroll
    for (int k = 0; k < 8; ++k) {
        int f = fl * 8 + k;
        pw[k] = (gact && f < F2) ? p2w[h * F2 + f] : 0.f;
    }
    const char* hb = (const char*)ht;
    for (int c = 0; c < 4; ++c) {
        int i = rh * 160 + wv * 40 + c * 10 + geff;
        float es = esl[i];
        int Lg = lenl[i];
        float t0 = es + M;
        float m = fmaxf(t0, LRA * t0);
        float acc[8];
        #pragma unroll
        for (int k = 0; k < 8; ++k) acc[k] = 0.f;
        float den = 0.f;
        const unsigned short* crow = cols16 + i * DEGCAP;
        int colv = crow[0];
        for (int j = 0; j < Lg; ++j) {
            int coln = (j + 1 < Lg) ? crow[j + 1] : 0;
            float t = es + edl[colv];
            t = fmaxf(t, LRA * t);
            float w = __expf(t - m);
            den += w;
            float4 qv = *(const float4*)(hb + (colv * 112 + fl * 16));
            int b0 = __float_as_int(qv.x);
            int b1 = __float_as_int(qv.y);
            int b2 = __float_as_int(qv.z);
            int b3 = __float_as_int(qv.w);
            acc[0] = fmaf(w, __int_as_float(b0 << 16), acc[0]);
            acc[1] = fmaf(w, __int_as_float(b0 & 0xffff0000), acc[1]);
            acc[2] = fmaf(w, __int_as_float(b1 << 16), acc[2]);
            acc[3] = fmaf(w, __int_as_float(b1 & 0xffff0000), acc[3]);
            acc[4] = fmaf(w, __int_as_float(b2 << 16), acc[4]);
            acc[5] = fmaf(w, __int_as_float(b2 & 0xffff0000), acc[5]);
            acc[6] = fmaf(w, __int_as_float(b3 << 16), acc[6]);
            acc[7] = fmaf(w, __int_as_float(b3 & 0xffff0000), acc[7]);
            colv = coln;
        }
        float inv = 1.f / den;
        float part = 0.f;
        #pragma unroll
        for (int k = 0; k < 8; ++k) {
            float v = acc[k] * inv;
            v = v > 0.f ? v : expm1f(v);
            part = fmaf(v, pw[k], part);
        }
        part += __shfl_down(part, 3, 64);
        float t1 = __shfl_down(part, 1, 64);
        float t2 = __shfl_down(part, 2, 64);
        part = part + t1 + t2;
        if (gact && fl == 0) part2[(size_t)bh * NN + i] = part;
    }
}

// ---- K5: x_concat assembly + FC head ---------------------------------------
__global__ __launch_bounds__(128) void k_head(
    const float* __restrict__ xn, const float* __restrict__ part1,
    const float* __restrict__ part2, const float* __restrict__ p1b,
    const float* __restrict__ p2b, const float* __restrict__ e1w,
    const float* __restrict__ e1b, const float* __restrict__ e2w,
    const float* __restrict__ e2b, const float* __restrict__ e3w,
    const float* __restrict__ e3b, const float* __restrict__ cw,
    const float* __restrict__ cb, float* __restrict__ dout) {
    int b = blockIdx.x;
    int tid = threadIdx.x;
    __shared__ float xc[960];
    __shared__ float h1[FC0];
    __shared__ float hh[FC1];
    __shared__ float ft[FC2];
    for (int t = tid; t < NN; t += 128) {
        float x0 = xn[b * NN + t];
        xc[t] = x0;
        dout[b * 960 + t] = x0;
        float s1 = p1b[0] + part1[(size_t)(b * 2) * NN + t] +
                   part1[(size_t)(b * 2 + 1) * NN + t];
        xc[320 + t] = s1;
        dout[b * 960 + 320 + t] = s1;
        float s2 = p2b[0];
        #pragma unroll
        for (int h = 0; h < 4; ++h) s2 += part2[(size_t)(b * 4 + h) * NN + t];
        xc[640 + t] = s2;
        dout[b * 960 + 640 + t] = s2;
    }
    __syncthreads();
    if (tid < FC0) {
        float a = e1b[tid];
        for (int k = 0; k < 960; ++k) a += xc[k] * e1w[k * FC0 + tid];
        h1[tid] = a > 0.f ? a : expm1f(a);
    }
    __syncthreads();
    if (tid < FC1) {
        float a = e2b[tid];
        for (int k = 0; k < FC0; ++k) a += h1[k] * e2w[k * FC1 + tid];
        hh[tid] = a > 0.f ? a : expm1f(a);
    }
    __syncthreads();
    if (tid < FC2) {
        float a = e3b[tid];
        for (int k = 0; k < FC1; ++k) a += hh[k] * e3w[k * FC2 + tid];
        a = a > 0.f ? a : expm1f(a);
        ft[tid] = a;
        dout[BS * 960 + b * FC2 + tid] = a;
    }
    __syncthreads();
    if (tid < 64) {
        float v = 0.f;
        for (int t = tid; t < FC2; t += 64) v += ft[t] * cw[t];
        v = wave_sum64(v);
        if (tid == 0) dout[BS * 960 + BS * FC2 + b] = v + cb[0];
    }
}

extern "C" void kernel_launch(void* const* d_in, const int* in_sizes, int n_in,
                              void* d_out, int out_size, void* d_ws,
                              size_t ws_size, hipStream_t stream) {
    const float* xn  = (const float*)d_in[0];
    const float* adj = (const float*)d_in[1];
    const float* W1  = (const float*)d_in[2];
    const float* a1  = (const float*)d_in[3];
    const float* W2  = (const float*)d_in[4];
    const float* a2  = (const float*)d_in[5];
    const float* p1w = (const float*)d_in[6];
    const float* p1b = (const float*)d_in[7];
    const float* p2w = (const float*)d_in[8];
    const float* p2b = (const float*)d_in[9];
    const float* e1w = (const float*)d_in[10];
    const float* e1b = (const float*)d_in[11];
    const float* e2w = (const float*)d_in[12];
    const float* e2b = (const float*)d_in[13];
    const float* e3w = (const float*)d_in[14];
    const float* e3b = (const float*)d_in[15];
    const float* cw  = (const float*)d_in[16];
    const float* cb  = (const float*)d_in[17];

    char* ws = (char*)d_ws;
    int*   csr_len  = (int*)ws;                                // [0, 1280)
    float* c1s      = (float*)(ws + 1280);
    float* c1d      = (float*)(ws + 1312);                     // pad -> 1536
    unsigned short* cols16  = (unsigned short*)(ws + 1536);    // 61440 -> 62976
    unsigned short* colsT16 = (unsigned short*)(ws + 62976);   // 61440 -> 124416
    __hip_bfloat16* Bb    = (__hip_bfloat16*)(ws + 124416);    // 61440 -> 185856
    __hip_bfloat16* out1b = (__hip_bfloat16*)(ws + 185856);    // 13107200 -> 13293056
    __hip_bfloat16* h2b   = (__hip_bfloat16*)(ws + 13293056);  // 18350080 -> 31643136
    float* part1    = (float*)(ws + 31643136);                 // 327680 -> 31970816
    float* part2    = (float*)(ws + 31970816);                 // 655360 -> 32626176
    float* dout     = (float*)d_out;

    k_csr<<<NN + 1 + 480, 64, 0, stream>>>(adj, cols16, colsT16, csr_len,
                                           W1, a1, c1s, c1d, W2, Bb);
    k_gat1<<<BS * 2, 320, 0, stream>>>(xn, colsT16, csr_len, W1, c1s, c1d,
                                       p1w, out1b, part1);
    k_gemm2<<<(BS * NN / 64) * 2, 256, 0, stream>>>(out1b, Bb, h2b);
    k_gat2<<<BS * H2C * 2, 256, 0, stream>>>(h2b, a2, cols16, csr_len, p2w, part2);
    k_head<<<BS, 128, 0, stream>>>(xn, part1, part2, p1b, p2b, e1w, e1b,
                                   e2w, e2b, e3w, e3b, cw, cb, dout);
}